// Round 5
// baseline (20883.644 us; speedup 1.0000x reference)
//
#include <hip/hip_runtime.h>

#define NR 4096
#define NT 720
#define TSEC 3600.0f
#define QLB 1e-4f
#define COLS_MAX 32768
#define RPW 8          // max rounds per wave (R <= 128 guaranteed for maxlev <= 63)
#define NWAVE 16

// ---------------- CSR build: count ----------------
__global__ void count_kernel(const float* __restrict__ adj, int* __restrict__ cnt) {
    int row = blockIdx.x;
    int lane = threadIdx.x;
    const float* r = adj + (size_t)row * NR;
    int c = 0;
    for (int base = 0; base < NR; base += 64) {
        float v = r[base + lane];
        unsigned long long m = __ballot(v != 0.0f);
        c += __popcll(m);
    }
    if (lane == 0) cnt[row] = c;
}

// ---------------- exclusive scan (single block, 1024 thr, 4/thread) ----------------
__global__ void scan_kernel(const int* __restrict__ cnt, int* __restrict__ rowptr) {
    __shared__ int part[1024];
    int tid = threadIdx.x;
    int base = tid * 4;
    int s0 = cnt[base], s1 = cnt[base + 1], s2 = cnt[base + 2], s3 = cnt[base + 3];
    int tot = s0 + s1 + s2 + s3;
    part[tid] = tot;
    __syncthreads();
    for (int off = 1; off < 1024; off <<= 1) {
        int v = part[tid];
        int add = (tid >= off) ? part[tid - off] : 0;
        __syncthreads();
        part[tid] = v + add;
        __syncthreads();
    }
    int excl = (tid > 0) ? part[tid - 1] : 0;
    rowptr[base]     = excl;
    rowptr[base + 1] = excl + s0;
    rowptr[base + 2] = excl + s0 + s1;
    rowptr[base + 3] = excl + s0 + s1 + s2;
    if (tid == 1023) rowptr[NR] = excl + tot;
}

// ---------------- CSR build: fill ----------------
__global__ void fill_kernel(const float* __restrict__ adj,
                            const int* __restrict__ rowptr, int* __restrict__ cols) {
    int row = blockIdx.x;
    int lane = threadIdx.x;
    const float* r = adj + (size_t)row * NR;
    int wbase = rowptr[row];
    for (int base = 0; base < NR; base += 64) {
        float v = r[base + lane];
        unsigned long long m = __ballot(v != 0.0f);
        if (v != 0.0f) {
            int pos = __popcll(m & ((1ull << lane) - 1ull));
            cols[wbase + pos] = base + lane;
        }
        wbase += __popcll(m);
    }
}

// ---------------- DAG levels (monotone Jacobi to fixpoint) ----------------
__global__ void level_kernel(const int* __restrict__ rowptr,
                             const int* __restrict__ cols, int* __restrict__ level_g) {
    __shared__ int lev[NR];
    __shared__ int changed;
    int tid = threadIdx.x;
#pragma unroll
    for (int k = 0; k < 4; k++) lev[tid + k * 1024] = 0;
    __syncthreads();
    for (int iter = 0; iter < NR; ++iter) {
        if (tid == 0) changed = 0;
        __syncthreads();
#pragma unroll
        for (int k = 0; k < 4; k++) {
            int i = tid + k * 1024;
            int b0 = rowptr[i], b1 = rowptr[i + 1];
            int m = 0;
            for (int e = b0; e < b1; e++) {
                int l = lev[cols[e]] + 1;
                m = (l > m) ? l : m;
            }
            if (b1 > b0 && m != lev[i]) { lev[i] = m; changed = 1; }
        }
        __syncthreads();
        if (changed == 0) break;
        __syncthreads();
    }
#pragma unroll
    for (int k = 0; k < 4; k++) level_g[tid + k * 1024] = lev[tid + k * 1024];
}

// ---------------- level sort: bitonic on (level<<12 | row), deterministic ----------------
__global__ void sort_kernel(const int* __restrict__ level_g, const int* __restrict__ cnt,
                            int* __restrict__ perm, int* __restrict__ inv,
                            int* __restrict__ lev_p, int* __restrict__ cnt_p,
                            int* __restrict__ meta) {
    __shared__ int keys[NR];
    int tid = threadIdx.x;
#pragma unroll
    for (int m = 0; m < 4; m++) {
        int i = tid + m * 1024;
        keys[i] = (level_g[i] << 12) | i;
    }
    __syncthreads();
    for (int ks = 2; ks <= NR; ks <<= 1) {
        for (int j = ks >> 1; j >= 1; j >>= 1) {
#pragma unroll
            for (int m = 0; m < 4; m++) {
                int i = tid + m * 1024;
                int p = i ^ j;
                if (p > i) {
                    bool up = ((i & ks) == 0);
                    int a = keys[i], b = keys[p];
                    if (up ? (a > b) : (a < b)) { keys[i] = b; keys[p] = a; }
                }
            }
            __syncthreads();
        }
    }
#pragma unroll
    for (int m = 0; m < 4; m++) {
        int p = tid + m * 1024;
        int key = keys[p];
        int row = key & (NR - 1);
        perm[p] = row;
        inv[row] = p;
        lev_p[p] = key >> 12;
        cnt_p[p] = cnt[row];
        if (row == NR - 1) meta[1] = p;       // gage sorted position
        if (p == NR - 1) meta[0] = key >> 12; // max level
    }
}

// ---------------- translate cols to sorted index space ----------------
__global__ void trans_kernel(const int* __restrict__ perm, const int* __restrict__ rowptr,
                             const int* __restrict__ cols, const int* __restrict__ inv,
                             const int* __restrict__ rowptr_p, int* __restrict__ cols_p) {
    int pos = blockIdx.x * blockDim.x + threadIdx.x;
    if (pos >= NR) return;
    int row = perm[pos];
    int b0 = rowptr[row];
    int n = rowptr[row + 1] - b0;
    int w = rowptr_p[pos];
    for (int j = 0; j < n; j++) cols_p[w + j] = inv[cols[b0 + j]];
}

// ---------------- coefficients (written in sorted order) ----------------
__global__ void coef_kernel(const int* __restrict__ perm,
                            const float* __restrict__ raw_n,
                            const float* __restrict__ raw_q,
                            const float* __restrict__ raw_p,
                            const float* __restrict__ width,
                            const float* __restrict__ length,
                            const float* __restrict__ slope,
                            const float* __restrict__ x_storage,
                            float* __restrict__ c1, float* __restrict__ c2,
                            float* __restrict__ c3, float* __restrict__ c4) {
    int pos = blockIdx.x * blockDim.x + threadIdx.x;
    if (pos >= NR) return;
    int i = perm[pos];
    float n   = 0.01f + raw_n[i] * (0.3f - 0.01f);
    float qsp = 1.5f + raw_q[i] * (3.0f - 1.5f);
    float psp = 0.5f + raw_p[i] * (2.0f - 0.5f);
    float s0  = fmaxf(slope[i], 1e-4f);
    float depth = logf(width[i] / psp) / logf(qsp);
    float v = (1.0f / n) * powf(depth, 2.0f / 3.0f) * sqrtf(s0);
    float c = fminf(fmaxf(v, 0.3f), 15.0f) * (5.0f / 3.0f);
    float k = length[i] / c;
    float x = x_storage[0];
    float denom = 2.0f * k * (1.0f - x) + TSEC;
    c1[pos] = (TSEC - 2.0f * k * x) / denom;
    c2[pos] = (TSEC + 2.0f * k * x) / denom;
    c3[pos] = (2.0f * k * (1.0f - x) - TSEC) / denom;
    c4[pos] = 2.0f * TSEC / denom;
}

// ---------------- round table: level-ordered <=64-row chunks ----------------
__global__ void meta3_kernel(const int* __restrict__ lev_p, const int* __restrict__ meta,
                             int* __restrict__ lstart, int* __restrict__ rtab) {
    int tid = threadIdx.x;
    int maxlev = meta[0];
    if (tid < 72) {  // lstart[l] = first sorted pos with level >= l
        int lo = 0, hi = NR;
        while (lo < hi) { int mid = (lo + hi) >> 1; if (lev_p[mid] < tid) lo = mid + 1; else hi = mid; }
        lstart[tid] = lo;
    }
    __syncthreads();
    if (tid == 0) {
        int R = 0;
        int lmax = (maxlev < 70) ? maxlev : 70;
        for (int l = 0; l <= lmax; l++) {
            int s = lstart[l], n = lstart[l + 1] - s;
            while (n > 0 && R < NWAVE * RPW) {
                int c = (n < 64) ? n : 64;
                rtab[2 + 2 * R] = s; rtab[3 + 2 * R] = c;
                s += c; n -= c; R++;
            }
        }
        rtab[0] = R;
    }
}

// ---------------- q pre-permute: qperm[t][pos] = qp[t][perm[pos]] ----------------
__global__ void qperm_kernel(const float* __restrict__ qp, const int* __restrict__ perm,
                             float* __restrict__ qperm) {
    int i = blockIdx.x * 256 + threadIdx.x;
    int t = blockIdx.y;
    if (i < NR) qperm[(size_t)t * NR + i] = qp[(size_t)t * NR + perm[i]];
}

// ---------------- main routing scan: wave-pipelined timesteps ----------------
// 16 waves own level-ordered round ranges. NO block barriers in the main loop;
// ordering via LDS monotone counters done[w] (acquire/release, workgroup scope).
// Wave w computes timestep t once done[w-1] >= t (transitively covers all lower
// waves). 4-deep ring sbuf[(t&3)*NR + pos]; overwrite of x(t-4) is safe once
// done[15] >= t-3. Semantics (verified rounds 3/4): buffers hold UNCLAMPED sol;
// clamp at consumption (prev reads, own-state, q, gage output).
template <bool QPERM>
__global__ __launch_bounds__(1024, 1) void route_pipe(
    const float* __restrict__ qp, const float* __restrict__ qperm,
    const float* __restrict__ c1g, const float* __restrict__ c2g,
    const float* __restrict__ c3g, const float* __restrict__ c4g,
    const int* __restrict__ rowptr_p, const int* __restrict__ cols_p,
    const int* __restrict__ perm, const int* __restrict__ meta,
    const int* __restrict__ rtab, float* __restrict__ out) {
    __shared__ float sbuf[4 * NR];
    __shared__ int done[NWAVE];
    int tid = threadIdx.x;
    int w = tid >> 6, lane = tid & 63;
    int gpos = meta[1];
    int R = rtab[0];
    int r0 = (w * R) >> 4;
    int r1 = ((w + 1) * R) >> 4;
    int nr = r1 - r0;

    // per-lane, per-round data in registers (ALL statically indexed)
    int pn_[RPW];                  // pos | (n<<12); -1 = inactive
    unsigned cw_[RPW][6];          // 12 cols packed 2x16b
    float C1_[RPW], C2_[RPW], C3_[RPW], C4_[RPW];
    int rowg_[RPW];                // original row (gather fallback only)
#pragma unroll
    for (int r = 0; r < RPW; r++) {
        pn_[r] = -1; rowg_[r] = 0;
        C1_[r] = 0.f; C2_[r] = 0.f; C3_[r] = 0.f; C4_[r] = 0.f;
#pragma unroll
        for (int h = 0; h < 6; h++) cw_[r][h] = 0u;
        if (r < nr) {
            int rs = rtab[2 + 2 * (r0 + r)], rc = rtab[3 + 2 * (r0 + r)];
            if (lane < rc) {
                int pos = rs + lane;
                int b0 = rowptr_p[pos];
                int n = rowptr_p[pos + 1] - b0;
                pn_[r] = pos | (n << 12);
#pragma unroll
                for (int h = 0; h < 6; h++) {
                    unsigned lo = (2 * h     < n) ? (unsigned)cols_p[b0 + 2 * h]     : 0u;
                    unsigned hi = (2 * h + 1 < n) ? (unsigned)cols_p[b0 + 2 * h + 1] : 0u;
                    cw_[r][h] = lo | (hi << 16);
                }
                C1_[r] = c1g[pos]; C2_[r] = c2g[pos];
                C3_[r] = c3g[pos]; C4_[r] = c4g[pos];
                if (!QPERM) rowg_[r] = perm[pos];
            }
        }
    }

    // init: slot 0 = x(0) = raw d0 (sorted order)
    for (int i = tid; i < NR; i += 1024)
        sbuf[i] = QPERM ? qperm[i] : qp[perm[i]];
    if (tid < NWAVE) done[tid] = 0;
    if (tid == 0) {
        float d0g = QPERM ? qperm[gpos] : qp[perm[gpos]];
        out[0] = fmaxf(d0g, QLB);
    }
    __syncthreads();

    // qlat for t=1 is q(0) = d0 = slot-0 values (read from LDS)
    float qlat_[RPW];
#pragma unroll
    for (int r = 0; r < RPW; r++)
        qlat_[r] = (pn_[r] >= 0) ? sbuf[pn_[r] & 0xFFF] : 0.f;

    for (int t = 1; t < NT; t++) {
        int cur = (t & 3) * NR;
        int prev = ((t - 1) & 3) * NR;
        // ring guard: all waves finished t-3 before slot (t&3) is overwritten
        if (t >= 4) {
            while (__hip_atomic_load(&done[NWAVE - 1], __ATOMIC_ACQUIRE,
                                     __HIP_MEMORY_SCOPE_WORKGROUP) < t - 3)
                __builtin_amdgcn_s_sleep(1);
        }
        // pipeline dependency: wave w-1 finished t (transitive over all lower)
        if (w > 0) {
            while (__hip_atomic_load(&done[w - 1], __ATOMIC_ACQUIRE,
                                     __HIP_MEMORY_SCOPE_WORKGROUP) < t)
                __builtin_amdgcn_s_sleep(1);
        }
#pragma unroll
        for (int r = 0; r < RPW; r++) {
            if (pn_[r] >= 0) {
                int pos = pn_[r] & 0xFFF;
                int n = pn_[r] >> 12;
                float sd = 0.f, sx = 0.f;
#pragma unroll
                for (int j = 0; j < 12; j++) {
                    if (j < n) {
                        unsigned cwv = cw_[r][j >> 1];
                        int c = (j & 1) ? (int)(cwv >> 16) : (int)(cwv & 0xFFFFu);
                        sd += fmaxf(sbuf[prev + c], QLB);
                        sx += sbuf[cur + c];
                    }
                }
                if (n > 12) {                      // ultra-rare overflow
                    int b0 = rowptr_p[pos];
                    for (int j = 12; j < n; j++) {
                        int c = cols_p[b0 + j];
                        sd += fmaxf(sbuf[prev + c], QLB);
                        sx += sbuf[cur + c];
                    }
                }
                float own = fmaxf(sbuf[prev + pos], QLB);
                float v = C2_[r] * sd + C3_[r] * own
                        + C4_[r] * fmaxf(qlat_[r], QLB) + C1_[r] * sx;
                sbuf[cur + pos] = v;               // unclamped sol
                if (pos == gpos) out[t] = fmaxf(v, QLB);
            }
        }
        // publish: release ensures all this wave's ds_writes are visible first
        if (lane == 0)
            __hip_atomic_store(&done[w], t, __ATOMIC_RELEASE,
                               __HIP_MEMORY_SCOPE_WORKGROUP);
        // prefetch q(t) for timestep t+1; latency hides under the next spin
        if (t < NT - 1) {
#pragma unroll
            for (int r = 0; r < RPW; r++) {
                if (pn_[r] >= 0) {
                    if (QPERM) qlat_[r] = qperm[(size_t)t * NR + (pn_[r] & 0xFFF)];
                    else       qlat_[r] = qp[(size_t)t * NR + rowg_[r]];
                }
            }
        }
    }
}

extern "C" void kernel_launch(void* const* d_in, const int* in_sizes, int n_in,
                              void* d_out, int out_size, void* d_ws, size_t ws_size,
                              hipStream_t stream) {
    const float* q_prime  = (const float*)d_in[0];
    const float* raw_n    = (const float*)d_in[1];
    const float* raw_q    = (const float*)d_in[2];
    const float* raw_p    = (const float*)d_in[3];
    const float* width    = (const float*)d_in[4];
    const float* length   = (const float*)d_in[5];
    const float* slope    = (const float*)d_in[6];
    const float* adj      = (const float*)d_in[7];
    const float* x_stor   = (const float*)d_in[8];
    float* out = (float*)d_out;

    // workspace layout (4B elems)
    float* ws_f = (float*)d_ws;
    float* c1p = ws_f;
    float* c2p = ws_f + NR;
    float* c3p = ws_f + 2 * NR;
    float* c4p = ws_f + 3 * NR;
    int* ws_i     = (int*)(ws_f + 4 * NR);
    int* cnt      = ws_i;                    // NR
    int* rowptr   = cnt + NR;                // NR+8
    int* cols     = rowptr + NR + 8;         // COLS_MAX
    int* level    = cols + COLS_MAX;         // NR
    int* perm     = level + NR;              // NR
    int* inv      = perm + NR;               // NR
    int* lev_p    = inv + NR;                // NR
    int* cnt_p    = lev_p + NR;              // NR
    int* rowptr_p = cnt_p + NR;              // NR+8
    int* cols_p   = rowptr_p + NR + 8;       // COLS_MAX
    int* meta     = cols_p + COLS_MAX;       // 8
    int* lstart   = meta + 8;                // 72
    int* rtab     = lstart + 72;             // 2 + 2*128 -> 272
    int* endbase  = rtab + 272;

    size_t base_bytes = (size_t)((char*)endbase - (char*)d_ws);
    size_t qoff = (base_bytes + 255) & ~(size_t)255;
    size_t qbytes = (size_t)NT * NR * sizeof(float);
    bool use_qperm = (ws_size >= qoff + qbytes);
    float* qperm = (float*)((char*)d_ws + qoff);

    count_kernel<<<NR, 64, 0, stream>>>(adj, cnt);
    scan_kernel<<<1, 1024, 0, stream>>>(cnt, rowptr);
    fill_kernel<<<NR, 64, 0, stream>>>(adj, rowptr, cols);
    level_kernel<<<1, 1024, 0, stream>>>(rowptr, cols, level);
    sort_kernel<<<1, 1024, 0, stream>>>(level, cnt, perm, inv, lev_p, cnt_p, meta);
    scan_kernel<<<1, 1024, 0, stream>>>(cnt_p, rowptr_p);
    trans_kernel<<<16, 256, 0, stream>>>(perm, rowptr, cols, inv, rowptr_p, cols_p);
    coef_kernel<<<16, 256, 0, stream>>>(perm, raw_n, raw_q, raw_p, width, length,
                                        slope, x_stor, c1p, c2p, c3p, c4p);
    meta3_kernel<<<1, 128, 0, stream>>>(lev_p, meta, lstart, rtab);
    if (use_qperm) {
        dim3 g(16, NT);
        qperm_kernel<<<g, 256, 0, stream>>>(q_prime, perm, qperm);
        route_pipe<true><<<1, 1024, 0, stream>>>(q_prime, qperm, c1p, c2p, c3p, c4p,
                                                 rowptr_p, cols_p, perm, meta, rtab, out);
    } else {
        route_pipe<false><<<1, 1024, 0, stream>>>(q_prime, qperm, c1p, c2p, c3p, c4p,
                                                  rowptr_p, cols_p, perm, meta, rtab, out);
    }
}

// Round 6
// 5583.704 us; speedup vs baseline: 3.7401x; 3.7401x over previous
//
#include <hip/hip_runtime.h>

#define NR 4096
#define NT 720
#define TSEC 3600.0f
#define QLB 1e-4f
#define COLS_MAX 32768
#define NB 8           // pipeline bands (1 wave each)
#define RPB 16         // max rounds per band (NB*RPB = 128 rounds capacity)
#define DEPTH 9        // LDS ring depth (>= NB+1)

// ---------------- CSR build: count ----------------
__global__ void count_kernel(const float* __restrict__ adj, int* __restrict__ cnt) {
    int row = blockIdx.x;
    int lane = threadIdx.x;
    const float* r = adj + (size_t)row * NR;
    int c = 0;
    for (int base = 0; base < NR; base += 64) {
        float v = r[base + lane];
        unsigned long long m = __ballot(v != 0.0f);
        c += __popcll(m);
    }
    if (lane == 0) cnt[row] = c;
}

// ---------------- exclusive scan (single block, 1024 thr, 4/thread) ----------------
__global__ void scan_kernel(const int* __restrict__ cnt, int* __restrict__ rowptr) {
    __shared__ int part[1024];
    int tid = threadIdx.x;
    int base = tid * 4;
    int s0 = cnt[base], s1 = cnt[base + 1], s2 = cnt[base + 2], s3 = cnt[base + 3];
    int tot = s0 + s1 + s2 + s3;
    part[tid] = tot;
    __syncthreads();
    for (int off = 1; off < 1024; off <<= 1) {
        int v = part[tid];
        int add = (tid >= off) ? part[tid - off] : 0;
        __syncthreads();
        part[tid] = v + add;
        __syncthreads();
    }
    int excl = (tid > 0) ? part[tid - 1] : 0;
    rowptr[base]     = excl;
    rowptr[base + 1] = excl + s0;
    rowptr[base + 2] = excl + s0 + s1;
    rowptr[base + 3] = excl + s0 + s1 + s2;
    if (tid == 1023) rowptr[NR] = excl + tot;
}

// ---------------- CSR build: fill ----------------
__global__ void fill_kernel(const float* __restrict__ adj,
                            const int* __restrict__ rowptr, int* __restrict__ cols) {
    int row = blockIdx.x;
    int lane = threadIdx.x;
    const float* r = adj + (size_t)row * NR;
    int wbase = rowptr[row];
    for (int base = 0; base < NR; base += 64) {
        float v = r[base + lane];
        unsigned long long m = __ballot(v != 0.0f);
        if (v != 0.0f) {
            int pos = __popcll(m & ((1ull << lane) - 1ull));
            cols[wbase + pos] = base + lane;
        }
        wbase += __popcll(m);
    }
}

// ---------------- DAG levels (monotone Jacobi to fixpoint) ----------------
__global__ void level_kernel(const int* __restrict__ rowptr,
                             const int* __restrict__ cols, int* __restrict__ level_g) {
    __shared__ int lev[NR];
    __shared__ int changed;
    int tid = threadIdx.x;
#pragma unroll
    for (int k = 0; k < 4; k++) lev[tid + k * 1024] = 0;
    __syncthreads();
    for (int iter = 0; iter < NR; ++iter) {
        if (tid == 0) changed = 0;
        __syncthreads();
#pragma unroll
        for (int k = 0; k < 4; k++) {
            int i = tid + k * 1024;
            int b0 = rowptr[i], b1 = rowptr[i + 1];
            int m = 0;
            for (int e = b0; e < b1; e++) {
                int l = lev[cols[e]] + 1;
                m = (l > m) ? l : m;
            }
            if (b1 > b0 && m != lev[i]) { lev[i] = m; changed = 1; }
        }
        __syncthreads();
        if (changed == 0) break;
        __syncthreads();
    }
#pragma unroll
    for (int k = 0; k < 4; k++) level_g[tid + k * 1024] = lev[tid + k * 1024];
}

// ---------------- level sort: bitonic on (level<<12 | row), deterministic ----------------
__global__ void sort_kernel(const int* __restrict__ level_g, const int* __restrict__ cnt,
                            int* __restrict__ perm, int* __restrict__ inv,
                            int* __restrict__ lev_p, int* __restrict__ cnt_p,
                            int* __restrict__ meta) {
    __shared__ int keys[NR];
    int tid = threadIdx.x;
#pragma unroll
    for (int m = 0; m < 4; m++) {
        int i = tid + m * 1024;
        keys[i] = (level_g[i] << 12) | i;
    }
    __syncthreads();
    for (int ks = 2; ks <= NR; ks <<= 1) {
        for (int j = ks >> 1; j >= 1; j >>= 1) {
#pragma unroll
            for (int m = 0; m < 4; m++) {
                int i = tid + m * 1024;
                int p = i ^ j;
                if (p > i) {
                    bool up = ((i & ks) == 0);
                    int a = keys[i], b = keys[p];
                    if (up ? (a > b) : (a < b)) { keys[i] = b; keys[p] = a; }
                }
            }
            __syncthreads();
        }
    }
#pragma unroll
    for (int m = 0; m < 4; m++) {
        int p = tid + m * 1024;
        int key = keys[p];
        int row = key & (NR - 1);
        perm[p] = row;
        inv[row] = p;
        lev_p[p] = key >> 12;
        cnt_p[p] = cnt[row];
        if (row == NR - 1) meta[1] = p;       // gage sorted position
        if (p == NR - 1) meta[0] = key >> 12; // max level
    }
}

// ---------------- translate cols to sorted index space ----------------
__global__ void trans_kernel(const int* __restrict__ perm, const int* __restrict__ rowptr,
                             const int* __restrict__ cols, const int* __restrict__ inv,
                             const int* __restrict__ rowptr_p, int* __restrict__ cols_p) {
    int pos = blockIdx.x * blockDim.x + threadIdx.x;
    if (pos >= NR) return;
    int row = perm[pos];
    int b0 = rowptr[row];
    int n = rowptr[row + 1] - b0;
    int w = rowptr_p[pos];
    for (int j = 0; j < n; j++) cols_p[w + j] = inv[cols[b0 + j]];
}

// ---------------- coefficients (written in sorted order) ----------------
__global__ void coef_kernel(const int* __restrict__ perm,
                            const float* __restrict__ raw_n,
                            const float* __restrict__ raw_q,
                            const float* __restrict__ raw_p,
                            const float* __restrict__ width,
                            const float* __restrict__ length,
                            const float* __restrict__ slope,
                            const float* __restrict__ x_storage,
                            float* __restrict__ c1, float* __restrict__ c2,
                            float* __restrict__ c3, float* __restrict__ c4) {
    int pos = blockIdx.x * blockDim.x + threadIdx.x;
    if (pos >= NR) return;
    int i = perm[pos];
    float n   = 0.01f + raw_n[i] * (0.3f - 0.01f);
    float qsp = 1.5f + raw_q[i] * (3.0f - 1.5f);
    float psp = 0.5f + raw_p[i] * (2.0f - 0.5f);
    float s0  = fmaxf(slope[i], 1e-4f);
    float depth = logf(width[i] / psp) / logf(qsp);
    float v = (1.0f / n) * powf(depth, 2.0f / 3.0f) * sqrtf(s0);
    float c = fminf(fmaxf(v, 0.3f), 15.0f) * (5.0f / 3.0f);
    float k = length[i] / c;
    float x = x_storage[0];
    float denom = 2.0f * k * (1.0f - x) + TSEC;
    c1[pos] = (TSEC - 2.0f * k * x) / denom;
    c2[pos] = (TSEC + 2.0f * k * x) / denom;
    c3[pos] = (2.0f * k * (1.0f - x) - TSEC) / denom;
    c4[pos] = 2.0f * TSEC / denom;
}

// ---------------- rounds + nnz-balanced band boundaries ----------------
// rtab[0]=R; rounds at rtab[2+2r]=(start) rtab[3+2r]=(count); barr[0..8] at rtab[260..268]
__global__ void meta4_kernel(const int* __restrict__ lev_p, const int* __restrict__ meta,
                             const int* __restrict__ rowptr_p,
                             int* __restrict__ lstart, int* __restrict__ rtab) {
    int tid = threadIdx.x;
    int maxlev = meta[0];
    if (tid < 72) {  // lstart[l] = first sorted pos with level >= l
        int lo = 0, hi = NR;
        while (lo < hi) { int mid = (lo + hi) >> 1; if (lev_p[mid] < tid) lo = mid + 1; else hi = mid; }
        lstart[tid] = lo;
    }
    __syncthreads();
    if (tid == 0) {
        int R = 0;
        float wt[NB * RPB];
        float total = 0.f;
        int lmax = (maxlev < 70) ? maxlev : 70;
        for (int l = 0; l <= lmax; l++) {
            int s = lstart[l], n = lstart[l + 1] - s;
            while (n > 0 && R < NB * RPB) {
                int c = (n < 64) ? n : 64;
                rtab[2 + 2 * R] = s; rtab[3 + 2 * R] = c;
                int nnz = rowptr_p[s + c] - rowptr_p[s];
                wt[R] = (float)c + 2.0f * (float)nnz;
                total += wt[R];
                s += c; n -= c; R++;
            }
        }
        rtab[0] = R;
        // greedy weight-balanced contiguous partition into NB bands, cap RPB
        int r = 0;
        float remw = total;
        rtab[260] = 0;
        for (int b = 0; b < NB; b++) {
            int rem = R - r;
            int maxt = (rem < RPB) ? rem : RPB;
            int mint = rem - (NB - 1 - b) * RPB;
            if (mint < 0) mint = 0;
            float tgt = remw / (float)(NB - b);
            int take = 0; float acc = 0.f;
            while (take < maxt) {
                if (take >= mint && acc >= tgt) break;
                acc += wt[r + take];
                take++;
            }
            r += take; remw -= acc;
            rtab[260 + b + 1] = r;
        }
    }
}

// ---------------- q pre-permute: qperm[t][pos] = qp[t][perm[pos]] ----------------
__global__ void qperm_kernel(const float* __restrict__ qp, const int* __restrict__ perm,
                             float* __restrict__ qperm) {
    int i = blockIdx.x * 256 + threadIdx.x;
    int t = blockIdx.y;
    if (i < NR) qperm[(size_t)t * NR + i] = qp[(size_t)t * NR + perm[i]];
}

// ---------------- main routing scan: 8-band wave pipeline, 9-deep LDS ring ----------------
// Band w (one wave) owns a contiguous level-ordered round range. Steady state:
// wave w lags wave w-1 by one timestep -> 1 stage + 1 handoff per timestep.
// Ring guard (wave0 only): done[7] >= t-8 before overwriting slot t%9.
// Semantics (proven R3-R5): sbuf holds UNCLAMPED sol; clamp at consumption.
template <bool QPERM>
__global__ __launch_bounds__(512, 2) void route_pipe(
    const float* __restrict__ qp, const float* __restrict__ qperm,
    const float* __restrict__ c1g, const float* __restrict__ c2g,
    const float* __restrict__ c3g, const float* __restrict__ c4g,
    const int* __restrict__ rowptr_p, const int* __restrict__ cols_p,
    const int* __restrict__ perm, const int* __restrict__ meta,
    const int* __restrict__ rtab, float* __restrict__ out) {
    __shared__ float sbuf[DEPTH * NR];   // 147456 B ring
    __shared__ int done[NB];
    int tid = threadIdx.x;
    int w = tid >> 6, lane = tid & 63;
    int gpos = meta[1];
    int r0 = rtab[260 + w];
    int nr = rtab[260 + w + 1] - r0;     // <= RPB

    // per-lane per-round registers (static indexing only)
    int pn_[RPB];                         // pos | (n<<12); -1 inactive
    unsigned cw_[RPB][4];                 // 8 cols packed 2x16b
    float C1_[RPB], C2_[RPB], C3_[RPB], C4_[RPB];
    float xprev_[RPB], qlat_[RPB];
    int rowg_[RPB];
#pragma unroll
    for (int r = 0; r < RPB; r++) {
        pn_[r] = -1; rowg_[r] = 0;
        C1_[r] = 0.f; C2_[r] = 0.f; C3_[r] = 0.f; C4_[r] = 0.f;
        xprev_[r] = 0.f; qlat_[r] = 0.f;
#pragma unroll
        for (int h = 0; h < 4; h++) cw_[r][h] = 0u;
        if (r < nr) {
            int rs = rtab[2 + 2 * (r0 + r)], rc = rtab[3 + 2 * (r0 + r)];
            if (lane < rc) {
                int pos = rs + lane;
                int b0 = rowptr_p[pos];
                int n = rowptr_p[pos + 1] - b0;
                pn_[r] = pos | (n << 12);
#pragma unroll
                for (int h = 0; h < 4; h++) {
                    unsigned lo = (2 * h     < n) ? (unsigned)cols_p[b0 + 2 * h]     : 0u;
                    unsigned hi = (2 * h + 1 < n) ? (unsigned)cols_p[b0 + 2 * h + 1] : 0u;
                    cw_[r][h] = lo | (hi << 16);
                }
                C1_[r] = c1g[pos]; C2_[r] = c2g[pos];
                C3_[r] = c3g[pos]; C4_[r] = c4g[pos];
                if (!QPERM) rowg_[r] = perm[pos];
            }
        }
    }

    // slot 0 = x(0) = raw d0 (sorted order)
    for (int i = tid; i < NR; i += 512)
        sbuf[i] = QPERM ? qperm[i] : qp[perm[i]];
    if (tid < NB) done[tid] = 0;
    if (tid == 0) {
        float d0g = QPERM ? qperm[gpos] : qp[perm[gpos]];
        out[0] = fmaxf(d0g, QLB);
    }
    __syncthreads();

    // own-state + q_lat(t=1) from slot 0
#pragma unroll
    for (int r = 0; r < RPB; r++) {
        if (pn_[r] >= 0) {
            float v = sbuf[pn_[r] & 0xFFF];
            xprev_[r] = v;
            qlat_[r] = v;
        }
    }

    int cur = NR, prev = 0;   // slots for t=1
    for (int t = 1; t < NT; t++) {
        if (w == 0) {
            if (t >= DEPTH) {
                while (__hip_atomic_load(&done[NB - 1], __ATOMIC_ACQUIRE,
                                         __HIP_MEMORY_SCOPE_WORKGROUP) < t - (DEPTH - 1))
                    __builtin_amdgcn_s_sleep(1);
            }
        } else {
            while (__hip_atomic_load(&done[w - 1], __ATOMIC_ACQUIRE,
                                     __HIP_MEMORY_SCOPE_WORKGROUP) < t)
                __builtin_amdgcn_s_sleep(1);
        }
#pragma unroll
        for (int r = 0; r < RPB; r++) {
            if (pn_[r] >= 0) {
                int pos = pn_[r] & 0xFFF;
                int n = pn_[r] >> 12;
                float sd = 0.f, sx = 0.f;
#pragma unroll
                for (int j = 0; j < 8; j++) {
                    if (j < n) {
                        unsigned cwv = cw_[r][j >> 1];
                        int c = (j & 1) ? (int)(cwv >> 16) : (int)(cwv & 0xFFFFu);
                        sd += fmaxf(sbuf[prev + c], QLB);
                        sx += sbuf[cur + c];
                    }
                }
                if (n > 8) {                       // rare deep-row overflow (L2)
                    int b0 = rowptr_p[pos];
                    for (int j = 8; j < n; j++) {
                        int c = cols_p[b0 + j];
                        sd += fmaxf(sbuf[prev + c], QLB);
                        sx += sbuf[cur + c];
                    }
                }
                float own = fmaxf(xprev_[r], QLB);
                float v = C2_[r] * sd + C3_[r] * own
                        + C4_[r] * fmaxf(qlat_[r], QLB) + C1_[r] * sx;
                sbuf[cur + pos] = v;               // unclamped sol
                xprev_[r] = v;
                if (pos == gpos) out[t] = fmaxf(v, QLB);
            }
        }
        if (lane == 0)
            __hip_atomic_store(&done[w], t, __ATOMIC_RELEASE,
                               __HIP_MEMORY_SCOPE_WORKGROUP);
        // prefetch q(t) for timestep t+1 (coalesced; hides under next spin)
        if (t < NT - 1) {
#pragma unroll
            for (int r = 0; r < RPB; r++) {
                if (pn_[r] >= 0) {
                    if (QPERM) qlat_[r] = qperm[(size_t)t * NR + (pn_[r] & 0xFFF)];
                    else       qlat_[r] = qp[(size_t)t * NR + rowg_[r]];
                }
            }
        }
        cur += NR;  if (cur == DEPTH * NR) cur = 0;
        prev += NR; if (prev == DEPTH * NR) prev = 0;
    }
}

extern "C" void kernel_launch(void* const* d_in, const int* in_sizes, int n_in,
                              void* d_out, int out_size, void* d_ws, size_t ws_size,
                              hipStream_t stream) {
    const float* q_prime  = (const float*)d_in[0];
    const float* raw_n    = (const float*)d_in[1];
    const float* raw_q    = (const float*)d_in[2];
    const float* raw_p    = (const float*)d_in[3];
    const float* width    = (const float*)d_in[4];
    const float* length   = (const float*)d_in[5];
    const float* slope    = (const float*)d_in[6];
    const float* adj      = (const float*)d_in[7];
    const float* x_stor   = (const float*)d_in[8];
    float* out = (float*)d_out;

    // workspace layout (4B elems)
    float* ws_f = (float*)d_ws;
    float* c1p = ws_f;
    float* c2p = ws_f + NR;
    float* c3p = ws_f + 2 * NR;
    float* c4p = ws_f + 3 * NR;
    int* ws_i     = (int*)(ws_f + 4 * NR);
    int* cnt      = ws_i;                    // NR
    int* rowptr   = cnt + NR;                // NR+8
    int* cols     = rowptr + NR + 8;         // COLS_MAX
    int* level    = cols + COLS_MAX;         // NR
    int* perm     = level + NR;              // NR
    int* inv      = perm + NR;               // NR
    int* lev_p    = inv + NR;                // NR
    int* cnt_p    = lev_p + NR;              // NR
    int* rowptr_p = cnt_p + NR;              // NR+8
    int* cols_p   = rowptr_p + NR + 8;       // COLS_MAX
    int* meta     = cols_p + COLS_MAX;       // 8
    int* lstart   = meta + 8;                // 72
    int* rtab     = lstart + 72;             // 272 (rounds + barr)
    int* endbase  = rtab + 272;

    size_t base_bytes = (size_t)((char*)endbase - (char*)d_ws);
    size_t qoff = (base_bytes + 255) & ~(size_t)255;
    size_t qbytes = (size_t)NT * NR * sizeof(float);
    bool use_qperm = (ws_size >= qoff + qbytes);
    float* qperm = (float*)((char*)d_ws + qoff);

    count_kernel<<<NR, 64, 0, stream>>>(adj, cnt);
    scan_kernel<<<1, 1024, 0, stream>>>(cnt, rowptr);
    fill_kernel<<<NR, 64, 0, stream>>>(adj, rowptr, cols);
    level_kernel<<<1, 1024, 0, stream>>>(rowptr, cols, level);
    sort_kernel<<<1, 1024, 0, stream>>>(level, cnt, perm, inv, lev_p, cnt_p, meta);
    scan_kernel<<<1, 1024, 0, stream>>>(cnt_p, rowptr_p);
    trans_kernel<<<16, 256, 0, stream>>>(perm, rowptr, cols, inv, rowptr_p, cols_p);
    coef_kernel<<<16, 256, 0, stream>>>(perm, raw_n, raw_q, raw_p, width, length,
                                        slope, x_stor, c1p, c2p, c3p, c4p);
    meta4_kernel<<<1, 128, 0, stream>>>(lev_p, meta, rowptr_p, lstart, rtab);
    if (use_qperm) {
        dim3 g(16, NT);
        qperm_kernel<<<g, 256, 0, stream>>>(q_prime, perm, qperm);
        route_pipe<true><<<1, 512, 0, stream>>>(q_prime, qperm, c1p, c2p, c3p, c4p,
                                                rowptr_p, cols_p, perm, meta, rtab, out);
    } else {
        route_pipe<false><<<1, 512, 0, stream>>>(q_prime, qperm, c1p, c2p, c3p, c4p,
                                                 rowptr_p, cols_p, perm, meta, rtab, out);
    }
}

// Round 7
// 5187.475 us; speedup vs baseline: 4.0258x; 1.0764x over previous
//
#include <hip/hip_runtime.h>

#define NR 4096
#define NT 720
#define TSEC 3600.0f
#define QLB 1e-4f
#define COLS_MAX 32768
#define NB 8           // pipeline bands (1 wave each)
#define RPB 16         // max rounds per band
#define DEPTH 9        // LDS ring depth (>= NB+1)

// ---------------- CSR build: count ----------------
__global__ void count_kernel(const float* __restrict__ adj, int* __restrict__ cnt) {
    int row = blockIdx.x;
    int lane = threadIdx.x;
    const float* r = adj + (size_t)row * NR;
    int c = 0;
    for (int base = 0; base < NR; base += 64) {
        float v = r[base + lane];
        unsigned long long m = __ballot(v != 0.0f);
        c += __popcll(m);
    }
    if (lane == 0) cnt[row] = c;
}

// ---------------- exclusive scan (single block, 1024 thr, 4/thread) ----------------
__global__ void scan_kernel(const int* __restrict__ cnt, int* __restrict__ rowptr) {
    __shared__ int part[1024];
    int tid = threadIdx.x;
    int base = tid * 4;
    int s0 = cnt[base], s1 = cnt[base + 1], s2 = cnt[base + 2], s3 = cnt[base + 3];
    int tot = s0 + s1 + s2 + s3;
    part[tid] = tot;
    __syncthreads();
    for (int off = 1; off < 1024; off <<= 1) {
        int v = part[tid];
        int add = (tid >= off) ? part[tid - off] : 0;
        __syncthreads();
        part[tid] = v + add;
        __syncthreads();
    }
    int excl = (tid > 0) ? part[tid - 1] : 0;
    rowptr[base]     = excl;
    rowptr[base + 1] = excl + s0;
    rowptr[base + 2] = excl + s0 + s1;
    rowptr[base + 3] = excl + s0 + s1 + s2;
    if (tid == 1023) rowptr[NR] = excl + tot;
}

// ---------------- CSR build: fill ----------------
__global__ void fill_kernel(const float* __restrict__ adj,
                            const int* __restrict__ rowptr, int* __restrict__ cols) {
    int row = blockIdx.x;
    int lane = threadIdx.x;
    const float* r = adj + (size_t)row * NR;
    int wbase = rowptr[row];
    for (int base = 0; base < NR; base += 64) {
        float v = r[base + lane];
        unsigned long long m = __ballot(v != 0.0f);
        if (v != 0.0f) {
            int pos = __popcll(m & ((1ull << lane) - 1ull));
            cols[wbase + pos] = base + lane;
        }
        wbase += __popcll(m);
    }
}

// ---------------- DAG levels (monotone Jacobi to fixpoint) ----------------
__global__ void level_kernel(const int* __restrict__ rowptr,
                             const int* __restrict__ cols, int* __restrict__ level_g) {
    __shared__ int lev[NR];
    __shared__ int changed;
    int tid = threadIdx.x;
#pragma unroll
    for (int k = 0; k < 4; k++) lev[tid + k * 1024] = 0;
    __syncthreads();
    for (int iter = 0; iter < NR; ++iter) {
        if (tid == 0) changed = 0;
        __syncthreads();
#pragma unroll
        for (int k = 0; k < 4; k++) {
            int i = tid + k * 1024;
            int b0 = rowptr[i], b1 = rowptr[i + 1];
            int m = 0;
            for (int e = b0; e < b1; e++) {
                int l = lev[cols[e]] + 1;
                m = (l > m) ? l : m;
            }
            if (b1 > b0 && m != lev[i]) { lev[i] = m; changed = 1; }
        }
        __syncthreads();
        if (changed == 0) break;
        __syncthreads();
    }
#pragma unroll
    for (int k = 0; k < 4; k++) level_g[tid + k * 1024] = lev[tid + k * 1024];
}

// ------ level sort: bitonic on (level<<18 | min(nnz,63)<<12 | row), deterministic ------
// nnz as secondary key makes each 64-row round degree-uniform -> wave-max n small.
__global__ void sort_kernel(const int* __restrict__ level_g, const int* __restrict__ cnt,
                            int* __restrict__ perm, int* __restrict__ inv,
                            int* __restrict__ lev_p, int* __restrict__ cnt_p,
                            int* __restrict__ meta) {
    __shared__ int keys[NR];
    int tid = threadIdx.x;
#pragma unroll
    for (int m = 0; m < 4; m++) {
        int i = tid + m * 1024;
        int nz = cnt[i]; nz = (nz < 63) ? nz : 63;
        keys[i] = (level_g[i] << 18) | (nz << 12) | i;
    }
    __syncthreads();
    for (int ks = 2; ks <= NR; ks <<= 1) {
        for (int j = ks >> 1; j >= 1; j >>= 1) {
#pragma unroll
            for (int m = 0; m < 4; m++) {
                int i = tid + m * 1024;
                int p = i ^ j;
                if (p > i) {
                    bool up = ((i & ks) == 0);
                    int a = keys[i], b = keys[p];
                    if (up ? (a > b) : (a < b)) { keys[i] = b; keys[p] = a; }
                }
            }
            __syncthreads();
        }
    }
#pragma unroll
    for (int m = 0; m < 4; m++) {
        int p = tid + m * 1024;
        int key = keys[p];
        int row = key & (NR - 1);
        perm[p] = row;
        inv[row] = p;
        lev_p[p] = key >> 18;
        cnt_p[p] = cnt[row];
        if (row == NR - 1) meta[1] = p;       // gage sorted position
        if (p == NR - 1) meta[0] = key >> 18; // max level
    }
}

// ---------------- translate cols to sorted index space ----------------
__global__ void trans_kernel(const int* __restrict__ perm, const int* __restrict__ rowptr,
                             const int* __restrict__ cols, const int* __restrict__ inv,
                             const int* __restrict__ rowptr_p, int* __restrict__ cols_p) {
    int pos = blockIdx.x * blockDim.x + threadIdx.x;
    if (pos >= NR) return;
    int row = perm[pos];
    int b0 = rowptr[row];
    int n = rowptr[row + 1] - b0;
    int w = rowptr_p[pos];
    for (int j = 0; j < n; j++) cols_p[w + j] = inv[cols[b0 + j]];
}

// ---------------- coefficients (written in sorted order) ----------------
__global__ void coef_kernel(const int* __restrict__ perm,
                            const float* __restrict__ raw_n,
                            const float* __restrict__ raw_q,
                            const float* __restrict__ raw_p,
                            const float* __restrict__ width,
                            const float* __restrict__ length,
                            const float* __restrict__ slope,
                            const float* __restrict__ x_storage,
                            float* __restrict__ c1, float* __restrict__ c2,
                            float* __restrict__ c3, float* __restrict__ c4) {
    int pos = blockIdx.x * blockDim.x + threadIdx.x;
    if (pos >= NR) return;
    int i = perm[pos];
    float n   = 0.01f + raw_n[i] * (0.3f - 0.01f);
    float qsp = 1.5f + raw_q[i] * (3.0f - 1.5f);
    float psp = 0.5f + raw_p[i] * (2.0f - 0.5f);
    float s0  = fmaxf(slope[i], 1e-4f);
    float depth = logf(width[i] / psp) / logf(qsp);
    float v = (1.0f / n) * powf(depth, 2.0f / 3.0f) * sqrtf(s0);
    float c = fminf(fmaxf(v, 0.3f), 15.0f) * (5.0f / 3.0f);
    float k = length[i] / c;
    float x = x_storage[0];
    float denom = 2.0f * k * (1.0f - x) + TSEC;
    c1[pos] = (TSEC - 2.0f * k * x) / denom;
    c2[pos] = (TSEC + 2.0f * k * x) / denom;
    c3[pos] = (2.0f * k * (1.0f - x) - TSEC) / denom;
    c4[pos] = 2.0f * TSEC / denom;
}

// ---------------- rounds + nnz-balanced band boundaries ----------------
__global__ void meta4_kernel(const int* __restrict__ lev_p, const int* __restrict__ meta,
                             const int* __restrict__ rowptr_p,
                             int* __restrict__ lstart, int* __restrict__ rtab) {
    int tid = threadIdx.x;
    int maxlev = meta[0];
    if (tid < 72) {  // lstart[l] = first sorted pos with level >= l
        int lo = 0, hi = NR;
        while (lo < hi) { int mid = (lo + hi) >> 1; if (lev_p[mid] < tid) lo = mid + 1; else hi = mid; }
        lstart[tid] = lo;
    }
    __syncthreads();
    if (tid == 0) {
        int R = 0;
        float wt[NB * RPB];
        float total = 0.f;
        int lmax = (maxlev < 70) ? maxlev : 70;
        for (int l = 0; l <= lmax; l++) {
            int s = lstart[l], n = lstart[l + 1] - s;
            while (n > 0 && R < NB * RPB) {
                int c = (n < 64) ? n : 64;
                rtab[2 + 2 * R] = s; rtab[3 + 2 * R] = c;
                int nnz = rowptr_p[s + c] - rowptr_p[s];
                wt[R] = (float)c + 2.0f * (float)nnz;
                total += wt[R];
                s += c; n -= c; R++;
            }
        }
        rtab[0] = R;
        int r = 0;
        float remw = total;
        rtab[260] = 0;
        for (int b = 0; b < NB; b++) {
            int rem = R - r;
            int maxt = (rem < RPB) ? rem : RPB;
            int mint = rem - (NB - 1 - b) * RPB;
            if (mint < 0) mint = 0;
            float tgt = remw / (float)(NB - b);
            int take = 0; float acc = 0.f;
            while (take < maxt) {
                if (take >= mint && acc >= tgt) break;
                acc += wt[r + take];
                take++;
            }
            r += take; remw -= acc;
            rtab[260 + b + 1] = r;
        }
    }
}

// ---------------- q pre-permute: qperm[t][pos] = qp[t][perm[pos]] ----------------
__global__ void qperm_kernel(const float* __restrict__ qp, const int* __restrict__ perm,
                             float* __restrict__ qperm) {
    int i = blockIdx.x * 256 + threadIdx.x;
    int t = blockIdx.y;
    if (i < NR) qperm[(size_t)t * NR + i] = qp[(size_t)t * NR + perm[i]];
}

// ---------------- main routing scan: 8-band wave pipeline, 9-deep LDS ring ----------------
// R7 deltas: (a) degree-uniform rounds + wave-max nmax (SGPR) guard -> ~3x fewer
// issued ds_reads; (b) relaxed handoff (explicit lgkmcnt(0), no vmcnt drain);
// (c) out[] buffered in LDS, dumped by gage-owner wave at the end.
// Semantics (proven R3-R6): sbuf holds UNCLAMPED sol; clamp at consumption.
template <bool QPERM>
__global__ __launch_bounds__(512, 1) void route_pipe(
    const float* __restrict__ qp, const float* __restrict__ qperm,
    const float* __restrict__ c1g, const float* __restrict__ c2g,
    const float* __restrict__ c3g, const float* __restrict__ c4g,
    const int* __restrict__ rowptr_p, const int* __restrict__ cols_p,
    const int* __restrict__ perm, const int* __restrict__ meta,
    const int* __restrict__ rtab, float* __restrict__ out) {
    __shared__ float sbuf[DEPTH * NR];   // 147456 B ring
    __shared__ float out_lds[NT];
    __shared__ int done[NB];
    int tid = threadIdx.x;
    int w = tid >> 6, lane = tid & 63;
    int gpos = meta[1];
    int r0 = rtab[260 + w];
    int nr = rtab[260 + w + 1] - r0;     // <= RPB

    // per-lane per-round registers (static indexing only)
    int pn_[RPB];                         // pos | (n<<12); -1 inactive
    unsigned cw_[RPB][4];                 // 8 cols packed 2x16b
    float C1_[RPB], C2_[RPB], C3_[RPB], C4_[RPB];
    float xprev_[RPB], qlat_[RPB];
    int rowg_[RPB];
    unsigned nmax_pk[(RPB + 3) / 4];      // per-round wave-max n, packed 4x8b (uniform)
#pragma unroll
    for (int h = 0; h < (RPB + 3) / 4; h++) nmax_pk[h] = 0u;
#pragma unroll
    for (int r = 0; r < RPB; r++) {
        pn_[r] = -1; rowg_[r] = 0;
        C1_[r] = 0.f; C2_[r] = 0.f; C3_[r] = 0.f; C4_[r] = 0.f;
        xprev_[r] = 0.f; qlat_[r] = 0.f;
#pragma unroll
        for (int h = 0; h < 4; h++) cw_[r][h] = 0u;
        int nlane = 0;
        if (r < nr) {
            int rs = rtab[2 + 2 * (r0 + r)], rc = rtab[3 + 2 * (r0 + r)];
            if (lane < rc) {
                int pos = rs + lane;
                int b0 = rowptr_p[pos];
                int n = rowptr_p[pos + 1] - b0;
                nlane = n;
                pn_[r] = pos | (n << 12);
#pragma unroll
                for (int h = 0; h < 4; h++) {
                    unsigned lo = (2 * h     < n) ? (unsigned)cols_p[b0 + 2 * h]     : 0u;
                    unsigned hi = (2 * h + 1 < n) ? (unsigned)cols_p[b0 + 2 * h + 1] : 0u;
                    cw_[r][h] = lo | (hi << 16);
                }
                C1_[r] = c1g[pos]; C2_[r] = c2g[pos];
                C3_[r] = c3g[pos]; C4_[r] = c4g[pos];
                if (!QPERM) rowg_[r] = perm[pos];
            }
        }
        // wave-max degree for this round -> SGPR, packed
        int nm = nlane;
#pragma unroll
        for (int off = 1; off < 64; off <<= 1) {
            int o = __shfl_xor(nm, off);
            nm = (o > nm) ? o : nm;
        }
        nm = __builtin_amdgcn_readfirstlane(nm);
        if (nm > 255) nm = 255;
        nmax_pk[r >> 2] |= ((unsigned)nm) << ((r & 3) * 8);
    }
#define NMAX(r) ((int)((nmax_pk[(r) >> 2] >> (((r) & 3) * 8)) & 0xFFu))

    // gage ownership (wave-level)
    bool own_l = false;
#pragma unroll
    for (int r = 0; r < RPB; r++)
        if (pn_[r] >= 0 && (pn_[r] & 0xFFF) == gpos) own_l = true;
    bool owner = (__ballot(own_l) != 0ull);

    // slot 0 = x(0) = raw d0 (sorted order)
    for (int i = tid; i < NR; i += 512)
        sbuf[i] = QPERM ? qperm[i] : qp[perm[i]];
    if (tid < NB) done[tid] = 0;
    if (tid == 0) {
        float d0g = QPERM ? qperm[gpos] : qp[perm[gpos]];
        out_lds[0] = fmaxf(d0g, QLB);
    }
    __syncthreads();

    // own-state + q_lat(t=1) from slot 0
#pragma unroll
    for (int r = 0; r < RPB; r++) {
        if (pn_[r] >= 0) {
            float v = sbuf[pn_[r] & 0xFFF];
            xprev_[r] = v;
            qlat_[r] = v;
        }
    }

    int cur = NR, prev = 0;   // slots for t=1
    for (int t = 1; t < NT; t++) {
        if (w == 0) {
            if (t >= DEPTH) {
                while (__hip_atomic_load(&done[NB - 1], __ATOMIC_ACQUIRE,
                                         __HIP_MEMORY_SCOPE_WORKGROUP) < t - (DEPTH - 1))
                    __builtin_amdgcn_s_sleep(1);
            }
        } else {
            while (__hip_atomic_load(&done[w - 1], __ATOMIC_ACQUIRE,
                                     __HIP_MEMORY_SCOPE_WORKGROUP) < t)
                __builtin_amdgcn_s_sleep(1);
        }
#pragma unroll
        for (int r = 0; r < RPB; r++) {
            if (pn_[r] >= 0) {
                int pos = pn_[r] & 0xFFF;
                int n = pn_[r] >> 12;
                float sd = 0.f, sx = 0.f;
#pragma unroll
                for (int j = 0; j < 8; j++) {
                    if (j < NMAX(r)) {            // uniform (SGPR) guard: skip empty slots
                        if (j < n) {              // per-lane mask
                            unsigned cwv = cw_[r][j >> 1];
                            int c = (j & 1) ? (int)(cwv >> 16) : (int)(cwv & 0xFFFFu);
                            sd += fmaxf(sbuf[prev + c], QLB);
                            sx += sbuf[cur + c];
                        }
                    }
                }
                if (n > 8) {                       // rare deep-row overflow (L2)
                    int b0 = rowptr_p[pos];
                    for (int j = 8; j < n; j++) {
                        int c = cols_p[b0 + j];
                        sd += fmaxf(sbuf[prev + c], QLB);
                        sx += sbuf[cur + c];
                    }
                }
                float own = fmaxf(xprev_[r], QLB);
                float v = C2_[r] * sd + C3_[r] * own
                        + C4_[r] * fmaxf(qlat_[r], QLB) + C1_[r] * sx;
                sbuf[cur + pos] = v;               // unclamped sol
                xprev_[r] = v;
                if (pos == gpos) out_lds[t] = fmaxf(v, QLB);
            }
        }
        // relaxed handoff: drain LDS only (no vmcnt) then plain flag store
        asm volatile("s_waitcnt lgkmcnt(0)" ::: "memory");
        if (lane == 0)
            __hip_atomic_store(&done[w], t, __ATOMIC_RELAXED,
                               __HIP_MEMORY_SCOPE_WORKGROUP);
        // prefetch q(t) for timestep t+1 (coalesced; hides under next spin)
        if (t < NT - 1) {
#pragma unroll
            for (int r = 0; r < RPB; r++) {
                if (pn_[r] >= 0) {
                    if (QPERM) qlat_[r] = qperm[(size_t)t * NR + (pn_[r] & 0xFFF)];
                    else       qlat_[r] = qp[(size_t)t * NR + rowg_[r]];
                }
            }
        }
        cur += NR;  if (cur == DEPTH * NR) cur = 0;
        prev += NR; if (prev == DEPTH * NR) prev = 0;
    }
    // gage-owner wave dumps the output series (its own lane wrote out_lds[1..])
    if (owner) {
        for (int i = lane; i < NT; i += 64) out[i] = out_lds[i];
    }
#undef NMAX
}

extern "C" void kernel_launch(void* const* d_in, const int* in_sizes, int n_in,
                              void* d_out, int out_size, void* d_ws, size_t ws_size,
                              hipStream_t stream) {
    const float* q_prime  = (const float*)d_in[0];
    const float* raw_n    = (const float*)d_in[1];
    const float* raw_q    = (const float*)d_in[2];
    const float* raw_p    = (const float*)d_in[3];
    const float* width    = (const float*)d_in[4];
    const float* length   = (const float*)d_in[5];
    const float* slope    = (const float*)d_in[6];
    const float* adj      = (const float*)d_in[7];
    const float* x_stor   = (const float*)d_in[8];
    float* out = (float*)d_out;

    // workspace layout (4B elems)
    float* ws_f = (float*)d_ws;
    float* c1p = ws_f;
    float* c2p = ws_f + NR;
    float* c3p = ws_f + 2 * NR;
    float* c4p = ws_f + 3 * NR;
    int* ws_i     = (int*)(ws_f + 4 * NR);
    int* cnt      = ws_i;                    // NR
    int* rowptr   = cnt + NR;                // NR+8
    int* cols     = rowptr + NR + 8;         // COLS_MAX
    int* level    = cols + COLS_MAX;         // NR
    int* perm     = level + NR;              // NR
    int* inv      = perm + NR;               // NR
    int* lev_p    = inv + NR;                // NR
    int* cnt_p    = lev_p + NR;              // NR
    int* rowptr_p = cnt_p + NR;              // NR+8
    int* cols_p   = rowptr_p + NR + 8;       // COLS_MAX
    int* meta     = cols_p + COLS_MAX;       // 8
    int* lstart   = meta + 8;                // 72
    int* rtab     = lstart + 72;             // 272 (rounds + band bounds)
    int* endbase  = rtab + 272;

    size_t base_bytes = (size_t)((char*)endbase - (char*)d_ws);
    size_t qoff = (base_bytes + 255) & ~(size_t)255;
    size_t qbytes = (size_t)NT * NR * sizeof(float);
    bool use_qperm = (ws_size >= qoff + qbytes);
    float* qperm = (float*)((char*)d_ws + qoff);

    count_kernel<<<NR, 64, 0, stream>>>(adj, cnt);
    scan_kernel<<<1, 1024, 0, stream>>>(cnt, rowptr);
    fill_kernel<<<NR, 64, 0, stream>>>(adj, rowptr, cols);
    level_kernel<<<1, 1024, 0, stream>>>(rowptr, cols, level);
    sort_kernel<<<1, 1024, 0, stream>>>(level, cnt, perm, inv, lev_p, cnt_p, meta);
    scan_kernel<<<1, 1024, 0, stream>>>(cnt_p, rowptr_p);
    trans_kernel<<<16, 256, 0, stream>>>(perm, rowptr, cols, inv, rowptr_p, cols_p);
    coef_kernel<<<16, 256, 0, stream>>>(perm, raw_n, raw_q, raw_p, width, length,
                                        slope, x_stor, c1p, c2p, c3p, c4p);
    meta4_kernel<<<1, 128, 0, stream>>>(lev_p, meta, rowptr_p, lstart, rtab);
    if (use_qperm) {
        dim3 g(16, NT);
        qperm_kernel<<<g, 256, 0, stream>>>(q_prime, perm, qperm);
        route_pipe<true><<<1, 512, 0, stream>>>(q_prime, qperm, c1p, c2p, c3p, c4p,
                                                rowptr_p, cols_p, perm, meta, rtab, out);
    } else {
        route_pipe<false><<<1, 512, 0, stream>>>(q_prime, qperm, c1p, c2p, c3p, c4p,
                                                 rowptr_p, cols_p, perm, meta, rtab, out);
    }
}